// Round 2
// baseline (521.079 us; speedup 1.0000x reference)
//
#include <hip/hip_runtime.h>
#include <hip/hip_bf16.h>

#define NC      80
#define BATCH   1048576
#define CHUNKS  (BATCH / 32)           // 32768 K-chunks of 32 rows
#define NBLK    768                    // 3 blocks/CU (LDS: 47.4 KB/block -> exactly 3/CU)
#define NTHR    256
#define NWAVES  (NBLK * NTHR / 64)     // 3072 waves, 10-11 chunks each
#define LDSW    17                     // dword stride per class row (odd -> bank spread)
#define WAVE_LDS (NC * LDSW)           // 1360 dwords per wave (5440 B)
#define NTILE   15                     // upper-triangle 16x16 tiles of 80x80
#define PART_ELEMS (NTILE * 256)       // 3840 floats per block partial

using bf16x8 = __attribute__((ext_vector_type(8))) __bf16;
using f32x4  = __attribute__((ext_vector_type(4))) float;

// Stage 1: G = label^T @ label (upper-triangle 16x16 tiles), bf16 MFMA.
// Labels are exactly {0,1} -> bf16 truncation exact; partial sums are ints
// < 2^24 -> fp32 accumulation exact and order-independent.
//
// Per chunk (32 rows x 80 cols f32), per wave:
//   - 10 coalesced global dwordx4 loads (lane i covers float4 #(i*64+lane)
//     of a row-PAIR decomposition: rows 2rp & 2rp+1 at cols 4c4..4c4+3)
//   - pack to bf16 k-pairs, write to wave-private transposed LDS
//     Lt[class][rp] (stride 17 dwords)
//   - 5 A/B fragments read as 4 contiguous dwords each
//   - 15 MFMAs (upper triangle; A-frag == B-frag memory pattern)
// No __syncthreads in the main loop (staging is wave-private).
__global__ __launch_bounds__(NTHR) void gram_kernel(const float* __restrict__ label,
                                                    float* __restrict__ part) {
    __shared__ unsigned int Lt[4 * WAVE_LDS];   // 21760 B staging (4 waves)
    __shared__ float Gs[NC * NC];               // 25600 B block accumulator

    const int tid  = threadIdx.x;
    const int lane = tid & 63;
    const int wv   = tid >> 6;
    const int m    = lane & 15;   // class-within-tile (frag row)
    const int quad = lane >> 4;   // k-subchunk selector
    unsigned int* lt = Lt + wv * WAVE_LDS;

    for (int u = tid; u < NC * NC; u += NTHR) Gs[u] = 0.0f;

    f32x4 acc[NTILE];
#pragma unroll
    for (int t = 0; t < NTILE; ++t) acc[t] = (f32x4){0.f, 0.f, 0.f, 0.f};

    // loop-invariant per-lane load/store decomposition
    int rp_[5], c4_[5];
#pragma unroll
    for (int i = 0; i < 5; ++i) {
        int p  = i * 64 + lane;    // float4-pair unit index, 0..319
        rp_[i] = p / 20;           // row-pair 0..15
        c4_[i] = p % 20;           // float4-within-row 0..19
    }

    const int wid = blockIdx.x * 4 + wv;

    for (int c = wid; c < CHUNKS; c += NWAVES) {
        const float* cb = label + (size_t)c * (32 * NC);
#pragma unroll
        for (int i = 0; i < 5; ++i) {
            const int rp = rp_[i], c4 = c4_[i];
            const float* pa = cb + (2 * rp) * NC + 4 * c4;
            float4 a = *(const float4*)pa;          // row 2rp   (k even)
            float4 b = *(const float4*)(pa + NC);   // row 2rp+1 (k odd)
            // bf16 truncation-pack: lo = even k, hi = odd k
            unsigned int p0 = (__float_as_uint(b.x) & 0xFFFF0000u) | (__float_as_uint(a.x) >> 16);
            unsigned int p1 = (__float_as_uint(b.y) & 0xFFFF0000u) | (__float_as_uint(a.y) >> 16);
            unsigned int p2 = (__float_as_uint(b.z) & 0xFFFF0000u) | (__float_as_uint(a.z) >> 16);
            unsigned int p3 = (__float_as_uint(b.w) & 0xFFFF0000u) | (__float_as_uint(a.w) >> 16);
            unsigned int base = (unsigned)(4 * c4) * LDSW + rp;
            lt[base]            = p0;
            lt[base + LDSW]     = p1;
            lt[base + 2 * LDSW] = p2;
            lt[base + 3 * LDSW] = p3;
        }

        // fragments: class = 16t + m, k-pairs quad*4 .. quad*4+3 (contiguous)
        bf16x8 frag[5];
#pragma unroll
        for (int t = 0; t < 5; ++t) {
            const unsigned int* fp = lt + (unsigned)(16 * t + m) * LDSW + quad * 4;
            union { unsigned int u[4]; bf16x8 b; } cv;
            cv.u[0] = fp[0]; cv.u[1] = fp[1]; cv.u[2] = fp[2]; cv.u[3] = fp[3];
            frag[t] = cv.b;
        }

        int idx = 0;
#pragma unroll
        for (int ti = 0; ti < 5; ++ti)
#pragma unroll
            for (int tj = ti; tj < 5; ++tj) {
                acc[idx] = __builtin_amdgcn_mfma_f32_16x16x32_bf16(
                    frag[ti], frag[tj], acc[idx], 0, 0, 0);
                ++idx;
            }
    }

    __syncthreads();   // Gs zero-init complete; all waves done with main loop

    // wave accs -> LDS (C/D layout: col = lane&15, row = quad*4 + reg)
    {
        int idx = 0;
#pragma unroll
        for (int ti = 0; ti < 5; ++ti)
#pragma unroll
            for (int tj = ti; tj < 5; ++tj) {
#pragma unroll
                for (int r = 0; r < 4; ++r) {
                    int row = 16 * ti + quad * 4 + r;
                    int col = 16 * tj + m;
                    atomicAdd(&Gs[row * NC + col], acc[idx][r]);
                }
                ++idx;
            }
    }
    __syncthreads();

    // block partial -> global (compact: part[block][tile][256]), no atomics
    {
        const int r  = tid >> 4;
        const int cl = tid & 15;
        float* pb = part + (size_t)blockIdx.x * PART_ELEMS;
        int t = 0;
#pragma unroll
        for (int ti = 0; ti < 5; ++ti)
#pragma unroll
            for (int tj = ti; tj < 5; ++tj) {
                pb[t * 256 + tid] = Gs[(16 * ti + r) * NC + (16 * tj + cl)];
                ++t;
            }
    }
}

// Stage 2a: reduce 768 block partials -> G (4-way split-K, 4 atomics/address)
__global__ __launch_bounds__(256) void reduce_kernel(const float* __restrict__ part,
                                                     float* __restrict__ G) {
    const int g = blockIdx.x * 256 + threadIdx.x;   // 0..15359 = 4 * 3840
    const int s = g / PART_ELEMS;                   // split-K slice 0..3
    const int v = g % PART_ELEMS;                   // partial element 0..3839
    const float* p = part + (size_t)s * (NBLK / 4) * PART_ELEMS + v;
    float sum = 0.f;
    for (int k = 0; k < NBLK / 4; ++k) sum += p[(size_t)k * PART_ELEMS];
    static const int TI[NTILE] = {0,0,0,0,0,1,1,1,1,2,2,2,3,3,4};
    static const int TJ[NTILE] = {0,1,2,3,4,1,2,3,4,2,3,4,3,4,4};
    const int t = v >> 8, e = v & 255, r = e >> 4, cl = e & 15;
    atomicAdd(&G[(16 * TI[t] + r) * NC + 16 * TJ[t] + cl], sum);
}

// Stage 2b: target = cooc/(count+eps) + eye ; smooth-L1-ish ; mean -> out[0]
__global__ __launch_bounds__(256) void loss_kernel(const float* __restrict__ pre_adj,
                                                   const float* __restrict__ G,
                                                   float* __restrict__ out) {
    const int tid = threadIdx.x;
    float sum = 0.f;
    for (int u = tid; u < NC * NC; u += 256) {
        int i = u / NC, j = u - i * NC;
        float target;
        if (i == j) {
            target = 1.0f;
        } else {
            // G stored only for tile(i) <= tile(j); G is symmetric
            float num = ((i >> 4) <= (j >> 4)) ? G[i * NC + j] : G[j * NC + i];
            float cnt = G[i * NC + i];   // count[i] = diag (binary labels)
            target = num / (cnt + 1e-7f);
        }
        float r = fabsf(pre_adj[u] - target);
        sum += (r < 1.0f) ? r * r : (r - 0.5f);
    }
#pragma unroll
    for (int off = 32; off > 0; off >>= 1) sum += __shfl_down(sum, off);
    __shared__ float ws[4];
    if ((tid & 63) == 0) ws[tid >> 6] = sum;
    __syncthreads();
    if (tid == 0) out[0] = (ws[0] + ws[1] + ws[2] + ws[3]) * (1.0f / 6400.0f);
}

extern "C" void kernel_launch(void* const* d_in, const int* in_sizes, int n_in,
                              void* d_out, int out_size, void* d_ws, size_t ws_size,
                              hipStream_t stream) {
    const float* pre_adj = (const float*)d_in[0];   // [80,80]
    const float* label   = (const float*)d_in[1];   // [1048576,80]
    float* out  = (float*)d_out;                    // scalar
    float* G    = (float*)d_ws;                     // 6400 f32
    float* part = (float*)d_ws + 8192;              // 768 * 3840 f32 = 11.8 MB

    hipMemsetAsync(G, 0, NC * NC * sizeof(float), stream);
    gram_kernel<<<NBLK, NTHR, 0, stream>>>(label, part);
    reduce_kernel<<<60, 256, 0, stream>>>(part, G);
    loss_kernel<<<1, 256, 0, stream>>>(pre_adj, G, out);
}